// Round 7
// baseline (781.759 us; speedup 1.0000x reference)
//
#include <hip/hip_runtime.h>

// ExtractSearchWindows: out[b,h,w,rr,tt] = (uint8)Q[b, h+off+ry+ty, w+off+rx+tx],
// Q = input padded by 6; stored as INT32.
//
// R14 theory: ten structural theories nulled (R3-R13: drains, barriers,
// occupancy 12/24/32 w/CU, duty cycle, bank conflicts, vmcnt retirement, line
// alignment, write-window size) -- kernel pinned at ~250us (2.9 TB/s) while
// the fill does 6.3 TB/s. The LAST component shared by every variant: LDS as
// the data source for every store (fill feeds stores from registers, no LDS).
// Ablate LDS entirely: input is 294KB = L1/L2-resident, so gather the 4 pixels
// of each quad DIRECTLY from global through L1 using register-resident rel
// offsets (fe[5][4], computed once per thread). No LDS, no staging, no
// barriers, no lgkmcnt, no tab kernel, no workspace. Interior groups (84%):
// unchecked base+rel loads. Border groups: block-uniform clamp+mask path.
// 512 blocks x 512 thr (2 blocks/CU, 16 waves/CU), block-per-group, 36 iters.

#define KT 7
#define K2 49
#define MAX_SR 3
#define B_ 2
#define H_ 192
#define W_ 192
#define HW (H_ * W_)
#define PAD 6
#define NT 512
#define NBLOCKS 512
#define NGROUPS (B_ * H_ * W_ / 4)    // 18432
#define NITER (NGROUPS / NBLOCKS)     // 36
#define RMAX 5                        // ceil(2401/512) quads per thread

typedef int vint4 __attribute__((ext_vector_type(4)));

// Image-relative offset (stride 192) of output dword jj within its group's
// 13x16 window anchored at (h-6, w-6). p_in shifts the anchor column by 1.
__device__ __forceinline__ int rel_entry(int jj, int cv, int offset, int d,
                                         int cvmagic) {
    if (jj >= 4 * d) jj = 4 * d - 1;            // clamp inactive tail
    int p_in = (jj >= d) + (jj >= 2 * d) + (jj >= 3 * d);
    int j  = jj - p_in * d;
    int rr = j / K2;                            // const divisor 49
    int tt = j - rr * K2;
    int ry = (rr * cvmagic) >> 16;              // rr / cv  (rr < 49)
    int rx = rr - ry * cv;
    int ty = tt / KT;                           // const divisor 7
    int tx = tt - ty * KT;
    return (offset + ry + ty) * W_ + (offset + rx + tx) + p_in;  // < 2320
}

__global__ __launch_bounds__(NT, 2) void esw_kernel(
    const float* __restrict__ in, int* __restrict__ out,
    int cv, int offset, int d, int cvmagic)
{
    const int tid = threadIdx.x;
    const int bid = blockIdx.x;

    // Register-resident offset table: quad q = tid + 512r, dwords 4q..4q+3.
    int fe[RMAX][4];
    #pragma unroll
    for (int r = 0; r < RMAX; ++r)
        #pragma unroll
        for (int u = 0; u < 4; ++u)
            fe[r][u] = rel_entry(4 * (tid + NT * r) + u, cv, offset, d, cvmagic);

    for (int it = 0; it < NITER; ++it) {
        const int g = it * NBLOCKS + bid;        // consecutive live groups
        const int pix0 = 4 * g;                  // W%4==0 -> group in one row
        const int b   = pix0 / HW;               // const-divisor magic
        const int rem = pix0 - b * HW;
        const int h   = rem / W_;
        const int w   = rem - h * W_;
        int* op = out + g * (4 * d);             // <=177M ints; 16B-aligned

        // Whole group's 13x16 window in-bounds? (block-uniform branch)
        const int interior = (h >= PAD) & (h + PAD < H_) &
                             (w >= PAD) & (w + 9 < W_);

        if (interior) {
            const float* bp = in + (b * HW + (h - PAD) * W_ + (w - PAD));
            #pragma unroll
            for (int r = 0; r < RMAX; ++r) {
                int q = tid + NT * r;
                if (q < d) {                     // r<4 full; r=4 masked
                    vint4 v;
                    v.x = (int)bp[fe[r][0]];     // L1-resident gather
                    v.y = (int)bp[fe[r][1]];
                    v.z = (int)bp[fe[r][2]];
                    v.w = (int)bp[fe[r][3]];
                    *(vint4*)(op + 4 * q) = v;
                }
            }
        } else {                                 // border: clamp + zero-mask
            const int bHW = b * HW;
            #pragma unroll
            for (int r = 0; r < RMAX; ++r) {
                int q = tid + NT * r;
                if (q < d) {
                    vint4 v;
                    #pragma unroll
                    for (int u = 0; u < 4; ++u) {
                        int rel = fe[r][u];
                        int dy  = (int)((((unsigned)rel >> 6) * 0xAAABu) >> 17); // rel/192
                        int dx  = rel - dy * W_;
                        int y   = h - PAD + dy;
                        int x   = w - PAD + dx;
                        int inb = ((unsigned)y < (unsigned)H_) &
                                  ((unsigned)x < (unsigned)W_);
                        int yc  = y < 0 ? 0 : (y > H_ - 1 ? H_ - 1 : y);
                        int xc  = x < 0 ? 0 : (x > W_ - 1 ? W_ - 1 : x);
                        int val = (int)in[bHW + yc * W_ + xc];
                        v[u] = inb ? val : 0;
                    }
                    *(vint4*)(op + 4 * q) = v;
                }
            }
        }
    }
}

extern "C" void kernel_launch(void* const* d_in, const int* in_sizes, int n_in,
                              void* d_out, int out_size, void* d_ws, size_t ws_size,
                              hipStream_t stream) {
    const float* in = (const float*)d_in[0];
    int* out = (int*)d_out;

    // out_size = B*H*W * cv^2 * 49
    int cv2 = out_size / (B_ * H_ * W_ * K2);
    int cv = 1;
    while (cv * cv < cv2) ++cv;
    int offset = MAX_SR - (cv - 1) / 2;
    int d = cv2 * K2;
    int cvmagic = 65536 / cv + 1;

    esw_kernel<<<NBLOCKS, NT, 0, stream>>>(in, out, cv, offset, d, cvmagic);
}

// Round 8
// 734.910 us; speedup vs baseline: 1.0637x; 1.0637x over previous
//
#include <hip/hip_runtime.h>

// ExtractSearchWindows: out[b,h,w,rr,tt] = (uint8)Q[b, h+off+ry+ty, w+off+rx+tx],
// Q = input padded by 6; stored as INT32.
//
// R15 theory: eleven structural theories nulled (R3-R13 all ~250us; R14's
// L1-direct gather REGRESSED to ~330us -> LDS-sourcing exonerated too). The
// one untested difference vs the 6.3 TB/s fill: store flavor. All our
// variants used regular global_store_dwordx4 -> every line ALLOCATES in the
// 32MB L2, then evicts+writes back 708MB of write-once data; if that
// allocate/writeback path caps ~3 TB/s, the kernel pins at ~250us regardless
// of issue-side structure (exactly what R3-R13 measured), while the fill's
// streaming stores bypass L2 at 6.3 TB/s. Fix (single variable on the R11
// base): __builtin_nontemporal_store for all output stores (gfx950 'nt'
// MUBUF flag, no L2 allocate). Everything else identical to R11: wave-private
// swizzled patch, zero s_barrier, L2-hot offset table prefetched 1 round
// ahead, stores never awaited. 512 blocks x 256 thr = 2048 waves.

#define KT 7
#define K2 49
#define MAX_SR 3
#define B_ 2
#define H_ 192
#define W_ 192
#define HW (H_ * W_)
#define PAD 6
#define NT 256
#define NBLOCKS 512
#define WPB (NT / 64)                 // 4 waves per block
#define NWAVES (NBLOCKS * WPB)        // 2048; 18432 groups / 2048 = 9 per wave
#define PS 17                         // patch row stride in element space
#define BUFI 280                      // swz(219)=273 -> pad to 280 ints
#define NGROUPS (B_ * H_ * W_ / 4)    // 18432
#define TABQ 2560                     // quads covered by table (>= 64*38+63)
#define TABN (4 * TABQ)               // 10240 ints

typedef int vint4 __attribute__((ext_vector_type(4)));

__device__ __forceinline__ int swz(int e) { return e + (e >> 2); }  // bijective

__device__ __forceinline__ int tab_entry(int jj, int cv, int offset, int d,
                                         int cvmagic) {
    if (jj >= 4 * d) jj = 4 * d - 1;            // clamp inactive tail
    int p_in = (jj >= d) + (jj >= 2 * d) + (jj >= 3 * d);
    int j  = jj - p_in * d;
    int rr = j / K2;                            // const divisor 49
    int tt = j - rr * K2;
    int ry = (rr * cvmagic) >> 16;              // rr / cv  (rr < 49)
    int rx = rr - ry * cv;
    int ty = tt / KT;                           // const divisor 7
    int tx = tt - ty * KT;
    int e = (offset + ry + ty) * PS + (offset + rx + tx) + p_in;
    return 4 * swz(e);                          // swizzled byte offset
}

__global__ __launch_bounds__(256) void tab_kernel(
    int* __restrict__ tab, int cv, int offset, int d, int cvmagic)
{
    int jj = blockIdx.x * 256 + threadIdx.x;
    if (jj < TABN) tab[jj] = tab_entry(jj, cv, offset, d, cvmagic);
}

__global__ __launch_bounds__(NT, 2) void esw_kernel(
    const float* __restrict__ in, int* __restrict__ out,
    const int* __restrict__ tab,
    int cv, int offset, int d, int cvmagic)
{
    __shared__ int patch[WPB][BUFI];

    const int tid  = threadIdx.x;
    const int lane = tid & 63;
    const int wv   = tid >> 6;
    int* const pbuf = patch[wv];                 // wave-private patch
    const char* const pb = (const char*)pbuf;

    const int NR  = (4 * d + 255) >> 8;          // gather rounds (<=38)
    const int wid = blockIdx.x * WPB + wv;

    for (int g = wid; g < NGROUPS; g += NWAVES) {
        // ---- stage the 13x16 neighborhood of this group's 4 pixels ----
        const int pix0 = 4 * g;                  // W%4==0 -> group in one row
        const int b   = pix0 / HW;
        const int rem = pix0 - b * HW;
        const int h   = rem / W_;
        const int w   = rem - h * W_;
        #pragma unroll
        for (int k = 0; k < 4; ++k) {
            int e = lane + 64 * k;               // k<3 full; k==3: lanes<16
            if (e < 13 * 16) {
                int dy = e >> 4, dx = e & 15;
                int y = h + dy - PAD, x = w + dx - PAD;
                int v = 0;
                if ((unsigned)y < (unsigned)H_ && (unsigned)x < (unsigned)W_)
                    v = (int)in[b * HW + y * W_ + x];
                pbuf[swz(dy * PS + dx)] = v;
            }
        }
        asm volatile("s_waitcnt lgkmcnt(0)" ::: "memory");  // patch ready
        // No s_barrier anywhere — patch is wave-private.

        // ---- gather + NONTEMPORAL store stream (no L2 allocate) ----
        int* op = out + g * (4 * d);             // <=177M ints, 32-bit safe
        if (tab) {
            vint4 t = *(const vint4*)(tab + 4 * lane);           // round 0
            for (int r = 0; r < NR; ++r) {
                vint4 tn = *(const vint4*)(tab + 4 * (64 * (r + 1) + lane));
                int q = 64 * r + lane;
                if (q < d) {                     // only last round masked
                    vint4 v;
                    v.x = *(const int*)(pb + t.x);
                    v.y = *(const int*)(pb + t.y);
                    v.z = *(const int*)(pb + t.z);
                    v.w = *(const int*)(pb + t.w);
                    __builtin_nontemporal_store(v, (vint4*)(op + 4 * q));
                }
                t = tn;
            }
        } else {                                 // no-workspace fallback
            for (int r = 0; r < NR; ++r) {
                int q = 64 * r + lane;
                if (q < d) {
                    vint4 v;
                    v.x = *(const int*)(pb + tab_entry(4 * q + 0, cv, offset, d, cvmagic));
                    v.y = *(const int*)(pb + tab_entry(4 * q + 1, cv, offset, d, cvmagic));
                    v.z = *(const int*)(pb + tab_entry(4 * q + 2, cv, offset, d, cvmagic));
                    v.w = *(const int*)(pb + tab_entry(4 * q + 3, cv, offset, d, cvmagic));
                    __builtin_nontemporal_store(v, (vint4*)(op + 4 * q));
                }
            }
        }
        // Next group's stage ds_writes must not bypass this group's reads.
        asm volatile("s_waitcnt lgkmcnt(0)" ::: "memory");
    }
}

extern "C" void kernel_launch(void* const* d_in, const int* in_sizes, int n_in,
                              void* d_out, int out_size, void* d_ws, size_t ws_size,
                              hipStream_t stream) {
    const float* in = (const float*)d_in[0];
    int* out = (int*)d_out;

    // out_size = B*H*W * cv^2 * 49
    int cv2 = out_size / (B_ * H_ * W_ * K2);
    int cv = 1;
    while (cv * cv < cv2) ++cv;
    int offset = MAX_SR - (cv - 1) / 2;
    int d = cv2 * K2;
    int cvmagic = 65536 / cv + 1;

    int* tab = (ws_size >= (size_t)(TABN * sizeof(int))) ? (int*)d_ws : nullptr;
    if (tab)
        tab_kernel<<<(TABN + 255) / 256, 256, 0, stream>>>(tab, cv, offset, d,
                                                           cvmagic);
    esw_kernel<<<NBLOCKS, NT, 0, stream>>>(in, out, tab, cv, offset, d, cvmagic);
}

// Round 9
// 692.876 us; speedup vs baseline: 1.1283x; 1.0607x over previous
//
#include <hip/hip_runtime.h>

// ExtractSearchWindows: out[b,h,w,rr,tt] = (uint8)Q[b, h+off+ry+ty, w+off+rx+tx],
// Q = input padded by 6; stored as INT32.
//
// R16: REVERT to best-measured variant (R11 structure, 693.2us). Session
// post-mortem: twelve orthogonal ablations bracket the kernel — store source
// (LDS / L1-direct / nontemporal), sync structure (0/1/2 barriers), occupancy
// (3-32 waves/CU), store duty cycle, LDS bank conflicts (stride-5 swizzle),
// vmcnt retirement order, 128B line alignment, write-window size (9.8MB-78MB),
// L2 cache policy both directions (allocate=baseline, nt=+40us WORSE). All
// structural changes null (~245us residual beyond the 450us harness poison
// fill); only genuine slowdowns register (R14 L1-gather +80us, R15 nt +40us).
// Conclusion: residual is dominated by fixed harness cost (2.83GB poison fill
// + tiny restore dispatches + launch overhead) with the kernel at/near the
// 112-130us write roofline for its 708MB output. esw never appears in top-5
// (<446us) across nine profiled runs. This is the roofline for this harness.
//
// Structure: one group per WAVE, wave-private swizzled patch (s(e)=e+(e>>2),
// stride-5 lanes -> conflict-free), ZERO s_barrier, L2-hot offset table
// prefetched one round ahead, stores never awaited. 512 blocks x 256 thr.

#define KT 7
#define K2 49
#define MAX_SR 3
#define B_ 2
#define H_ 192
#define W_ 192
#define HW (H_ * W_)
#define PAD 6
#define NT 256
#define NBLOCKS 512
#define WPB (NT / 64)                 // 4 waves per block
#define NWAVES (NBLOCKS * WPB)        // 2048; 18432 groups / 2048 = 9 per wave
#define PS 17                         // patch row stride in element space
#define BUFI 280                      // swz(219)=273 -> pad to 280 ints
#define NGROUPS (B_ * H_ * W_ / 4)    // 18432
#define TABQ 2560                     // quads covered by table (>= 64*38+63)
#define TABN (4 * TABQ)               // 10240 ints

typedef int vint4 __attribute__((ext_vector_type(4)));

__device__ __forceinline__ int swz(int e) { return e + (e >> 2); }  // bijective

__device__ __forceinline__ int tab_entry(int jj, int cv, int offset, int d,
                                         int cvmagic) {
    if (jj >= 4 * d) jj = 4 * d - 1;            // clamp inactive tail
    int p_in = (jj >= d) + (jj >= 2 * d) + (jj >= 3 * d);
    int j  = jj - p_in * d;
    int rr = j / K2;                            // const divisor 49
    int tt = j - rr * K2;
    int ry = (rr * cvmagic) >> 16;              // rr / cv  (rr < 49)
    int rx = rr - ry * cv;
    int ty = tt / KT;                           // const divisor 7
    int tx = tt - ty * KT;
    int e = (offset + ry + ty) * PS + (offset + rx + tx) + p_in;
    return 4 * swz(e);                          // swizzled byte offset
}

__global__ __launch_bounds__(256) void tab_kernel(
    int* __restrict__ tab, int cv, int offset, int d, int cvmagic)
{
    int jj = blockIdx.x * 256 + threadIdx.x;
    if (jj < TABN) tab[jj] = tab_entry(jj, cv, offset, d, cvmagic);
}

__global__ __launch_bounds__(NT, 2) void esw_kernel(
    const float* __restrict__ in, int* __restrict__ out,
    const int* __restrict__ tab,
    int cv, int offset, int d, int cvmagic)
{
    __shared__ int patch[WPB][BUFI];

    const int tid  = threadIdx.x;
    const int lane = tid & 63;
    const int wv   = tid >> 6;
    int* const pbuf = patch[wv];                 // wave-private patch
    const char* const pb = (const char*)pbuf;

    const int NR  = (4 * d + 255) >> 8;          // gather rounds (<=38)
    const int wid = blockIdx.x * WPB + wv;

    for (int g = wid; g < NGROUPS; g += NWAVES) {
        // ---- stage the 13x16 neighborhood of this group's 4 pixels ----
        const int pix0 = 4 * g;                  // W%4==0 -> group in one row
        const int b   = pix0 / HW;
        const int rem = pix0 - b * HW;
        const int h   = rem / W_;
        const int w   = rem - h * W_;
        #pragma unroll
        for (int k = 0; k < 4; ++k) {
            int e = lane + 64 * k;               // k<3 full; k==3: lanes<16
            if (e < 13 * 16) {
                int dy = e >> 4, dx = e & 15;
                int y = h + dy - PAD, x = w + dx - PAD;
                int v = 0;
                if ((unsigned)y < (unsigned)H_ && (unsigned)x < (unsigned)W_)
                    v = (int)in[b * HW + y * W_ + x];
                pbuf[swz(dy * PS + dx)] = v;
            }
        }
        asm volatile("s_waitcnt lgkmcnt(0)" ::: "memory");  // patch ready
        // No s_barrier anywhere — patch is wave-private.

        // ---- gather + uninterrupted store stream: NR x 1KB per wave ----
        int* op = out + g * (4 * d);             // <=177M ints, 32-bit safe
        if (tab) {
            vint4 t = *(const vint4*)(tab + 4 * lane);           // round 0
            for (int r = 0; r < NR; ++r) {
                // prefetch next round's offsets (64*NR+63 < TABQ always)
                vint4 tn = *(const vint4*)(tab + 4 * (64 * (r + 1) + lane));
                int q = 64 * r + lane;
                if (q < d) {                     // only last round masked
                    vint4 v;
                    v.x = *(const int*)(pb + t.x);
                    v.y = *(const int*)(pb + t.y);
                    v.z = *(const int*)(pb + t.z);
                    v.w = *(const int*)(pb + t.w);
                    *(vint4*)(op + 4 * q) = v;
                }
                t = tn;
            }
        } else {                                 // no-workspace fallback
            for (int r = 0; r < NR; ++r) {
                int q = 64 * r + lane;
                if (q < d) {
                    vint4 v;
                    v.x = *(const int*)(pb + tab_entry(4 * q + 0, cv, offset, d, cvmagic));
                    v.y = *(const int*)(pb + tab_entry(4 * q + 1, cv, offset, d, cvmagic));
                    v.z = *(const int*)(pb + tab_entry(4 * q + 2, cv, offset, d, cvmagic));
                    v.w = *(const int*)(pb + tab_entry(4 * q + 3, cv, offset, d, cvmagic));
                    *(vint4*)(op + 4 * q) = v;
                }
            }
        }
        // Next group's stage ds_writes must not bypass this group's reads.
        asm volatile("s_waitcnt lgkmcnt(0)" ::: "memory");
    }
}

extern "C" void kernel_launch(void* const* d_in, const int* in_sizes, int n_in,
                              void* d_out, int out_size, void* d_ws, size_t ws_size,
                              hipStream_t stream) {
    const float* in = (const float*)d_in[0];
    int* out = (int*)d_out;

    // out_size = B*H*W * cv^2 * 49
    int cv2 = out_size / (B_ * H_ * W_ * K2);
    int cv = 1;
    while (cv * cv < cv2) ++cv;
    int offset = MAX_SR - (cv - 1) / 2;
    int d = cv2 * K2;
    int cvmagic = 65536 / cv + 1;

    int* tab = (ws_size >= (size_t)(TABN * sizeof(int))) ? (int*)d_ws : nullptr;
    if (tab)
        tab_kernel<<<(TABN + 255) / 256, 256, 0, stream>>>(tab, cv, offset, d,
                                                           cvmagic);
    esw_kernel<<<NBLOCKS, NT, 0, stream>>>(in, out, tab, cv, offset, d, cvmagic);
}